// Round 1
// baseline (325.433 us; speedup 1.0000x reference)
//
#include <hip/hip_runtime.h>
#include <math.h>

typedef unsigned short u16;
typedef __attribute__((ext_vector_type(8))) short bf16x8;
typedef __attribute__((ext_vector_type(4))) float f32x4;

#define MFMA16(a, b, c) __builtin_amdgcn_mfma_f32_16x16x32_bf16((a), (b), (c), 0, 0, 0)

#define B_ 2
#define S_ 2048
#define HID_ 2048
#define NH_ 16
#define NKV_ 4
#define HD_ 128
#define SCALE_ 0.08838834764831845f

static __device__ __forceinline__ u16 f2bf(float f) {
  unsigned u = __float_as_uint(f);
  u = (u + 0x7FFFu + ((u >> 16) & 1u)) >> 16;
  return (u16)u;
}

#define GLDS(src, dst)                                                        \
  __builtin_amdgcn_global_load_lds(                                           \
      (const __attribute__((address_space(1))) void*)(src),                   \
      (__attribute__((address_space(3))) void*)(dst), 16, 0, 0)

// Stage a tile (rows x (1<<CPRL) 16B-chunks per row) from global into LDS.
// LDS layout is linear with XOR swizzle baked in via pre-swizzled SOURCE
// address (global_load_lds dest must be linear: base + lane*16).
// LDS[r][bir] holds global[r][bir ^ ((r&7)<<4)].
template <int CPRL>
static __device__ __forceinline__ void stage_tile(const char* g0, long gstride,
                                                  char* lds) {
  int tid = threadIdx.x;
  int lane = tid & 63, wv = tid >> 6;
#pragma unroll
  for (int it = 0; it < 4; ++it) {
    int cb = wv * 256 + it * 64;  // wave-uniform chunk base
    int c = cb + lane;
    int r = c >> CPRL;
    int bir = (c & ((1 << CPRL) - 1)) << 4;
    int sbir = bir ^ ((r & 7) << 4);
    GLDS(g0 + (long)r * gstride + sbir, lds + cb * 16);
  }
}

// ---------------- prep kernels ----------------

__global__ __launch_bounds__(256) void conv_x(const float* __restrict__ x,
                                              u16* __restrict__ y) {
  size_t i = ((size_t)blockIdx.x * 256 + threadIdx.x) * 4;
  float4 v = *(const float4*)(x + i);
  ushort4 o = make_ushort4(f2bf(v.x), f2bf(v.y), f2bf(v.z), f2bf(v.w));
  *(ushort4*)(y + i) = o;
}

// dst[n*K + k] = bf16(src[k*N + n]);  grid: (N/32, K/32), block (32,8)
__global__ __launch_bounds__(256) void transpose_bf16(
    const float* __restrict__ src, u16* __restrict__ dst, int K, int N) {
  __shared__ float t[32][33];
  int n0 = blockIdx.x * 32, k0 = blockIdx.y * 32;
  int tx = threadIdx.x, ty = threadIdx.y;
#pragma unroll
  for (int i = 0; i < 4; ++i)
    t[ty + 8 * i][tx] = src[(size_t)(k0 + ty + 8 * i) * N + n0 + tx];
  __syncthreads();
#pragma unroll
  for (int i = 0; i < 4; ++i)
    dst[(size_t)(n0 + ty + 8 * i) * K + k0 + tx] = f2bf(t[tx][ty + 8 * i]);
}

__global__ __launch_bounds__(256) void prep_cstab(const int* __restrict__ pos,
                                                  float2* __restrict__ cs) {
  int i = blockIdx.x * 256 + threadIdx.x;  // [B*S * 64)
  int row = i >> 6, d = i & 63;
  double p = (double)pos[row];
  double inv = exp(-((double)(2 * d) / 128.0) * log(1000000.0));
  double a = p * inv;
  cs[i] = make_float2((float)cos(a), (float)sin(a));
}

// ---------------- GEMM1: QKV projection + bias + RoPE ----------------
// C[4096,3072] = Xb[4096,2048] @ Wqkv_t^T ; BM=BN=128, BK=64
// wave tile: 32 rows x 128 cols (so RoPE pairs d,d+64 are lane-local)
__global__ __launch_bounds__(256) void gemm_qkv(
    const u16* __restrict__ Xb, const u16* __restrict__ Wt,
    const float* __restrict__ bq, const float* __restrict__ bk,
    const float* __restrict__ bv, const float2* __restrict__ cstab,
    u16* __restrict__ Qh, u16* __restrict__ Kh, u16* __restrict__ Vt) {
  __shared__ __align__(16) char As[16384];
  __shared__ __align__(16) char Bs[16384];
  int bm = blockIdx.x, bn = blockIdx.y;
  int tid = threadIdx.x, lane = tid & 63, w = tid >> 6;
  int l16 = lane & 15, ln4 = lane >> 4;

  f32x4 acc[2][8] = {};

  for (int kt = 0; kt < 32; ++kt) {
    __syncthreads();
    stage_tile<3>((const char*)(Xb + (size_t)bm * 128 * 2048 + kt * 64), 4096,
                  As);
    stage_tile<3>((const char*)(Wt + (size_t)bn * 128 * 2048 + kt * 64), 4096,
                  Bs);
    __syncthreads();
#pragma unroll
    for (int kk = 0; kk < 2; ++kk) {
      bf16x8 a[2], b[8];
#pragma unroll
      for (int m = 0; m < 2; ++m) {
        int r = w * 32 + m * 16 + l16;
        int off = r * 128 + ((kk * 64 + ln4 * 16) ^ ((r & 7) << 4));
        a[m] = *(const bf16x8*)(As + off);
      }
#pragma unroll
      for (int n = 0; n < 8; ++n) {
        int r = n * 16 + l16;
        int off = r * 128 + ((kk * 64 + ln4 * 16) ^ ((r & 7) << 4));
        b[n] = *(const bf16x8*)(Bs + off);
      }
#pragma unroll
      for (int m = 0; m < 2; ++m)
#pragma unroll
        for (int n = 0; n < 8; ++n) acc[m][n] = MFMA16(a[m], b[n], acc[m][n]);
    }
  }

  // epilogue: bias + RoPE + scatter to Q/K/V buffers
  int region, hh;
  const float* bias;
  if (bn < 16) {
    region = 0; hh = bn; bias = bq;
  } else if (bn < 20) {
    region = 1; hh = bn - 16; bias = bk;
  } else {
    region = 2; hh = bn - 20; bias = bv;
  }

#pragma unroll
  for (int bi = 0; bi < 4; ++bi) {
    int dlo = bi * 16 + l16;  // 0..63
    float blo = bias[hh * 128 + dlo];
    float bhi = bias[hh * 128 + dlo + 64];
#pragma unroll
    for (int m = 0; m < 2; ++m) {
      int rbase = bm * 128 + w * 32 + m * 16 + ln4 * 4;
      int bb = rbase >> 11;   // batch
      int s0 = rbase & 2047;  // seq
      if (region == 2) {
        // V: no rope; transposed store Vt[b][kvh][d][s], 4 consecutive s
        u16 pl[4], ph[4];
#pragma unroll
        for (int reg = 0; reg < 4; ++reg) {
          pl[reg] = f2bf(acc[m][bi][reg] + blo);
          ph[reg] = f2bf(acc[m][bi + 4][reg] + bhi);
        }
        size_t base = ((size_t)(bb * NKV_ + hh) * 128 + dlo) * 2048 + s0;
        *(ushort4*)(Vt + base) = make_ushort4(pl[0], pl[1], pl[2], pl[3]);
        *(ushort4*)(Vt + base + (size_t)64 * 2048) =
            make_ushort4(ph[0], ph[1], ph[2], ph[3]);
      } else {
#pragma unroll
        for (int reg = 0; reg < 4; ++reg) {
          int rg = rbase + reg;
          int s = rg & 2047;
          float vlo = acc[m][bi][reg] + blo;
          float vhi = acc[m][bi + 4][reg] + bhi;
          float2 cs = cstab[(size_t)rg * 64 + dlo];
          float nl = vlo * cs.x - vhi * cs.y;
          float nh = vhi * cs.x + vlo * cs.y;
          u16* dst = (region == 0)
                         ? Qh + ((size_t)(bb * NH_ + hh) * 2048 + s) * 128
                         : Kh + ((size_t)(bb * NKV_ + hh) * 2048 + s) * 128;
          dst[dlo] = f2bf(nl);
          dst[dlo + 64] = f2bf(nh);
        }
      }
    }
  }
}

// ---------------- attention: causal GQA flash ----------------
// block: 256 thr / 4 waves; wave w owns q rows [q0+w*16, +16); KV tile 64
__global__ __launch_bounds__(256) void attn(const u16* __restrict__ Qh,
                                            const u16* __restrict__ Kh,
                                            const u16* __restrict__ Vt,
                                            u16* __restrict__ ctx) {
  __shared__ __align__(16) char Ks[16384];   // [64 kv][128 d] swizzled
  __shared__ __align__(16) char Vs[16384];   // [128 d][64 kv] swizzled
  __shared__ __align__(16) char Ps[4][2048]; // per-wave [16 q][64 kv] swizzled
  int qt = blockIdx.x, h = blockIdx.y, b = blockIdx.z;
  int q0 = qt * 64;
  int kvh = h >> 2;
  int tid = threadIdx.x, lane = tid & 63, w = tid >> 6;
  int l16 = lane & 15, ln4 = lane >> 4;

  // Q fragments (registers), rows q0+w*16+l16
  bf16x8 qf[4];
  const u16* qrow = Qh + ((size_t)(b * NH_ + h) * 2048 + q0 + w * 16 + l16) * 128;
#pragma unroll
  for (int kk = 0; kk < 4; ++kk)
    qf[kk] = *(const bf16x8*)(qrow + kk * 32 + ln4 * 8);

  f32x4 oacc[8] = {};
  float mrow[4], lsum[4];
#pragma unroll
  for (int r = 0; r < 4; ++r) {
    mrow[r] = -1e30f;
    lsum[r] = 0.0f;
  }

  const char* kbase = (const char*)(Kh + (size_t)(b * NKV_ + kvh) * 2048 * 128);
  const char* vbase = (const char*)(Vt + (size_t)(b * NKV_ + kvh) * 128 * 2048);

  for (int t = 0; t <= qt; ++t) {
    __syncthreads();
    stage_tile<4>(kbase + (size_t)t * 64 * 256, 256, Ks);
    stage_tile<3>(vbase + (size_t)t * 128, 4096, Vs);
    __syncthreads();

    // S = Q K^T
    f32x4 sa[4] = {};
#pragma unroll
    for (int kk = 0; kk < 4; ++kk) {
      bf16x8 kf[4];
#pragma unroll
      for (int n = 0; n < 4; ++n) {
        int r = n * 16 + l16;
        int off = r * 256 + ((kk * 64 + ln4 * 16) ^ ((r & 7) << 4));
        kf[n] = *(const bf16x8*)(Ks + off);
      }
#pragma unroll
      for (int n = 0; n < 4; ++n) sa[n] = MFMA16(qf[kk], kf[n], sa[n]);
    }

    // online softmax (rows q = ln4*4+reg, cols kv = n*16+l16)
    float scl[4];
    bool last = (t == qt);
#pragma unroll
    for (int reg = 0; reg < 4; ++reg) {
      int qg = q0 + w * 16 + ln4 * 4 + reg;
      float sv[4];
#pragma unroll
      for (int n = 0; n < 4; ++n) {
        sv[n] = sa[n][reg] * SCALE_;
        int kvg = t * 64 + n * 16 + l16;
        if (last && kvg > qg) sv[n] = -1e30f;
      }
      float tm = fmaxf(fmaxf(sv[0], sv[1]), fmaxf(sv[2], sv[3]));
      for (int mk = 1; mk < 16; mk <<= 1) tm = fmaxf(tm, __shfl_xor(tm, mk));
      float mnew = fmaxf(mrow[reg], tm);
      scl[reg] = __expf(mrow[reg] - mnew);
      float rs = 0.0f;
      int prow = ln4 * 4 + reg;
#pragma unroll
      for (int n = 0; n < 4; ++n) {
        float p = __expf(sv[n] - mnew);
        rs += p;
        int off = prow * 128 + ((2 * (n * 16 + l16)) ^ ((prow & 7) << 4));
        *(u16*)(Ps[w] + off) = f2bf(p);
      }
      for (int mk = 1; mk < 16; mk <<= 1) rs += __shfl_xor(rs, mk);
      lsum[reg] = lsum[reg] * scl[reg] + rs;
      mrow[reg] = mnew;
    }
    // rescale O
#pragma unroll
    for (int nf = 0; nf < 8; ++nf)
#pragma unroll
      for (int reg = 0; reg < 4; ++reg) oacc[nf][reg] *= scl[reg];

    // O += P V   (A = P from wave-private LDS, B = Vt)
#pragma unroll
    for (int kc = 0; kc < 2; ++kc) {
      int offa = l16 * 128 + ((kc * 64 + ln4 * 16) ^ ((l16 & 7) << 4));
      bf16x8 pa = *(const bf16x8*)(Ps[w] + offa);
#pragma unroll
      for (int nf = 0; nf < 8; ++nf) {
        int r = nf * 16 + l16;
        int off = r * 128 + ((kc * 64 + ln4 * 16) ^ ((r & 7) << 4));
        bf16x8 vf = *(const bf16x8*)(Vs + off);
        oacc[nf] = MFMA16(pa, vf, oacc[nf]);
      }
    }
  }

  // write ctx[b][s][h*128 + d] bf16
#pragma unroll
  for (int reg = 0; reg < 4; ++reg) {
    float inv = 1.0f / lsum[reg];
    int s = q0 + w * 16 + ln4 * 4 + reg;
#pragma unroll
    for (int nf = 0; nf < 8; ++nf) {
      ctx[((size_t)(b * 2048 + s)) * 2048 + h * 128 + nf * 16 + l16] =
          f2bf(oacc[nf][reg] * inv);
    }
  }
}

// ---------------- GEMM2: out = ctx @ Wo (fp32 out) ----------------
__global__ __launch_bounds__(256) void gemm_out(const u16* __restrict__ Ab,
                                                const u16* __restrict__ Wt,
                                                float* __restrict__ out) {
  __shared__ __align__(16) char As[16384];
  __shared__ __align__(16) char Bs[16384];
  int bm = blockIdx.x, bn = blockIdx.y;
  int tid = threadIdx.x, lane = tid & 63, w = tid >> 6;
  int l16 = lane & 15, ln4 = lane >> 4;
  int wr = (w >> 1) * 64, wc = (w & 1) * 64;

  f32x4 acc[4][4] = {};

  for (int kt = 0; kt < 32; ++kt) {
    __syncthreads();
    stage_tile<3>((const char*)(Ab + (size_t)bm * 128 * 2048 + kt * 64), 4096,
                  As);
    stage_tile<3>((const char*)(Wt + (size_t)bn * 128 * 2048 + kt * 64), 4096,
                  Bs);
    __syncthreads();
#pragma unroll
    for (int kk = 0; kk < 2; ++kk) {
      bf16x8 a[4], b[4];
#pragma unroll
      for (int m = 0; m < 4; ++m) {
        int r = wr + m * 16 + l16;
        int off = r * 128 + ((kk * 64 + ln4 * 16) ^ ((r & 7) << 4));
        a[m] = *(const bf16x8*)(As + off);
      }
#pragma unroll
      for (int n = 0; n < 4; ++n) {
        int r = wc + n * 16 + l16;
        int off = r * 128 + ((kk * 64 + ln4 * 16) ^ ((r & 7) << 4));
        b[n] = *(const bf16x8*)(Bs + off);
      }
#pragma unroll
      for (int m = 0; m < 4; ++m)
#pragma unroll
        for (int n = 0; n < 4; ++n) acc[m][n] = MFMA16(a[m], b[n], acc[m][n]);
    }
  }

#pragma unroll
  for (int m = 0; m < 4; ++m)
#pragma unroll
    for (int n = 0; n < 4; ++n)
#pragma unroll
      for (int reg = 0; reg < 4; ++reg) {
        int row = bm * 128 + wr + m * 16 + ln4 * 4 + reg;
        int col = bn * 128 + wc + n * 16 + l16;
        out[(size_t)row * 2048 + col] = acc[m][n][reg];
      }
}

// ---------------- launch ----------------

extern "C" void kernel_launch(void* const* d_in, const int* in_sizes, int n_in,
                              void* d_out, int out_size, void* d_ws,
                              size_t ws_size, hipStream_t stream) {
  const float* hid = (const float*)d_in[0];
  const int* pos = (const int*)d_in[1];
  const float* Wq = (const float*)d_in[2];
  const float* bq = (const float*)d_in[3];
  const float* Wk = (const float*)d_in[4];
  const float* bk = (const float*)d_in[5];
  const float* Wv = (const float*)d_in[6];
  const float* bv = (const float*)d_in[7];
  const float* Wo = (const float*)d_in[8];
  float* out = (float*)d_out;

  char* ws = (char*)d_ws;
  u16* Xb = (u16*)(ws + 0);                    // 16.78 MB  [4096][2048] bf16
  u16* Wqkvt = (u16*)(ws + 16777216UL);        // 12.58 MB  [3072][2048] bf16
  u16* Wot = (u16*)(ws + 29360128UL);          //  8.39 MB  [2048][2048] bf16
  u16* Qh = (u16*)(ws + 37748736UL);           // 16.78 MB  [B][NH][S][D]
  u16* Kh = (u16*)(ws + 54525952UL);           //  4.19 MB  [B][NKV][S][D]
  u16* Vt = (u16*)(ws + 58720256UL);           //  4.19 MB  [B][NKV][D][S]
  float2* cstab = (float2*)(ws + 62914560UL);  //  2.10 MB  [B*S][64]
  u16* ctx = Xb;  // alias: Xb dead after gemm_qkv

  conv_x<<<8192, 256, 0, stream>>>(hid, Xb);
  transpose_bf16<<<dim3(64, 64), dim3(32, 8), 0, stream>>>(Wq, Wqkvt, 2048,
                                                           2048);
  transpose_bf16<<<dim3(16, 64), dim3(32, 8), 0, stream>>>(
      Wk, Wqkvt + (size_t)2048 * 2048, 2048, 512);
  transpose_bf16<<<dim3(16, 64), dim3(32, 8), 0, stream>>>(
      Wv, Wqkvt + (size_t)2560 * 2048, 2048, 512);
  transpose_bf16<<<dim3(64, 64), dim3(32, 8), 0, stream>>>(Wo, Wot, 2048, 2048);
  prep_cstab<<<1024, 256, 0, stream>>>(pos, cstab);

  gemm_qkv<<<dim3(32, 24), 256, 0, stream>>>(Xb, Wqkvt, bq, bk, bv, cstab, Qh,
                                             Kh, Vt);
  attn<<<dim3(32, 16, 2), 256, 0, stream>>>(Qh, Kh, Vt, ctx);
  gemm_out<<<dim3(32, 16), 256, 0, stream>>>(ctx, Wot, out);
}